// Round 1
// baseline (86.591 us; speedup 1.0000x reference)
//
#include <hip/hip_runtime.h>
#include <math.h>

#define DDIM 128
#define NB   2048
#define NC   1000
#define EPSV 1e-6f

// ws layout (float offsets). Rewritten every launch (stats kernel), no state carried.
#define WS_PROTO 0
#define WS_SUMF  64
#define WS_NF    (WS_SUMF + NB)          // 64+2048
#define WS_SUMW  (WS_NF + NB)            // 64+4096
#define WS_NW    (WS_SUMW + 1024)        // 64+5120
// total 64+2048+2048+1024+1024 = 6208 floats (~25 KB) << ws_size

// ---------------- per-row stats: sum and sum-of-squares, one wave per row ---------
__global__ __launch_bounds__(256) void stats_kernel(const float* __restrict__ F,
                                                    const float* __restrict__ Wm,
                                                    float* __restrict__ ws) {
    if (blockIdx.x == 0 && threadIdx.x == 0) ws[WS_PROTO] = 0.0f;  // zero atomic target
    int gw   = (blockIdx.x * 256 + threadIdx.x) >> 6;
    int lane = threadIdx.x & 63;
    if (gw >= NB + NC) return;
    const float* row;
    int so, no, idx;
    if (gw < NB) { idx = gw;      row = F  + idx * DDIM; so = WS_SUMF; no = WS_NF; }
    else         { idx = gw - NB; row = Wm + idx * DDIM; so = WS_SUMW; no = WS_NW; }
    float2 v = *(const float2*)(row + lane * 2);
    float s = v.x + v.y;
    float q = v.x * v.x + v.y * v.y;
    #pragma unroll
    for (int off = 32; off > 0; off >>= 1) {
        s += __shfl_down(s, off);
        q += __shfl_down(q, off);
    }
    if (lane == 0) { ws[so + idx] = s; ws[no + idx] = q; }
}

// ---------------- proto: sum_{c1,c2} ||w_c1 - w_c2 + eps||  -> ws[WS_PROTO] -------
__global__ __launch_bounds__(256) void proto_kernel(const float* __restrict__ Wm,
                                                    float* __restrict__ ws) {
    __shared__ __align__(16) float As[64][68];  // As[k][m] transposed tile
    __shared__ __align__(16) float Bs[64][68];
    __shared__ float red[4];
    int t  = threadIdx.x;
    int tx = t & 15, ty = t >> 4;
    int row0 = blockIdx.y * 64, col0 = blockIdx.x * 64;
    float acc[4][4] = {};
    for (int kc = 0; kc < DDIM; kc += 64) {
        #pragma unroll
        for (int it = 0; it < 4; ++it) {
            int r  = ty + 16 * it;
            int gr = row0 + r; if (gr > NC - 1) gr = NC - 1;
            float4 g = *(const float4*)(Wm + gr * DDIM + kc + tx * 4);
            As[tx*4+0][r] = g.x; As[tx*4+1][r] = g.y; As[tx*4+2][r] = g.z; As[tx*4+3][r] = g.w;
            int gc = col0 + r; if (gc > NC - 1) gc = NC - 1;
            float4 h = *(const float4*)(Wm + gc * DDIM + kc + tx * 4);
            Bs[tx*4+0][r] = h.x; Bs[tx*4+1][r] = h.y; Bs[tx*4+2][r] = h.z; Bs[tx*4+3][r] = h.w;
        }
        __syncthreads();
        #pragma unroll 8
        for (int k = 0; k < 64; ++k) {
            float4 a = *(const float4*)&As[k][ty * 4];
            float4 b = *(const float4*)&Bs[k][tx * 4];
            float av[4] = {a.x, a.y, a.z, a.w};
            float bv[4] = {b.x, b.y, b.z, b.w};
            #pragma unroll
            for (int i = 0; i < 4; ++i)
                #pragma unroll
                for (int j = 0; j < 4; ++j)
                    acc[i][j] = fmaf(av[i], bv[j], acc[i][j]);
        }
        __syncthreads();
    }
    const float de2 = DDIM * EPSV * EPSV;
    float local = 0.0f;
    #pragma unroll
    for (int i = 0; i < 4; ++i) {
        int c1 = row0 + ty * 4 + i;
        if (c1 < NC) {
            float q1 = ws[WS_NW + c1] + 2.0f * EPSV * ws[WS_SUMW + c1];
            #pragma unroll
            for (int j = 0; j < 4; ++j) {
                int c2 = col0 + tx * 4 + j;
                if (c2 < NC) {
                    float q2 = ws[WS_NW + c2] - 2.0f * EPSV * ws[WS_SUMW + c2];
                    float d2 = q1 + q2 + de2 - 2.0f * acc[i][j];
                    local += sqrtf(fmaxf(d2, 0.0f));
                }
            }
        }
    }
    #pragma unroll
    for (int off = 32; off > 0; off >>= 1) local += __shfl_down(local, off);
    if ((t & 63) == 0) red[t >> 6] = local;
    __syncthreads();
    if (t == 0) atomicAdd(&ws[WS_PROTO], red[0] + red[1] + red[2] + red[3]);
}

// ---------------- main: out[b,c] = proto - ||f_b - w_c + eps|| --------------------
__global__ __launch_bounds__(256) void dist_kernel(const float* __restrict__ F,
                                                   const float* __restrict__ Wm,
                                                   const float* __restrict__ ws,
                                                   float* __restrict__ out) {
    __shared__ __align__(16) float As[64][68];
    __shared__ __align__(16) float Bs[64][68];
    int t  = threadIdx.x;
    int tx = t & 15, ty = t >> 4;
    int row0 = blockIdx.y * 64, col0 = blockIdx.x * 64;
    float acc[4][4] = {};
    for (int kc = 0; kc < DDIM; kc += 64) {
        #pragma unroll
        for (int it = 0; it < 4; ++it) {
            int r = ty + 16 * it;
            float4 g = *(const float4*)(F + (row0 + r) * DDIM + kc + tx * 4);
            As[tx*4+0][r] = g.x; As[tx*4+1][r] = g.y; As[tx*4+2][r] = g.z; As[tx*4+3][r] = g.w;
            int gc = col0 + r; if (gc > NC - 1) gc = NC - 1;
            float4 h = *(const float4*)(Wm + gc * DDIM + kc + tx * 4);
            Bs[tx*4+0][r] = h.x; Bs[tx*4+1][r] = h.y; Bs[tx*4+2][r] = h.z; Bs[tx*4+3][r] = h.w;
        }
        __syncthreads();
        #pragma unroll 8
        for (int k = 0; k < 64; ++k) {
            float4 a = *(const float4*)&As[k][ty * 4];
            float4 b = *(const float4*)&Bs[k][tx * 4];
            float av[4] = {a.x, a.y, a.z, a.w};
            float bv[4] = {b.x, b.y, b.z, b.w};
            #pragma unroll
            for (int i = 0; i < 4; ++i)
                #pragma unroll
                for (int j = 0; j < 4; ++j)
                    acc[i][j] = fmaf(av[i], bv[j], acc[i][j]);
        }
        __syncthreads();
    }
    float proto = ws[WS_PROTO];
    const float de2 = DDIM * EPSV * EPSV;
    int cbase = col0 + tx * 4;
    float pw[4];
    #pragma unroll
    for (int j = 0; j < 4; ++j) {
        int c = cbase + j;
        pw[j] = (c < NC) ? (ws[WS_NW + c] - 2.0f * EPSV * ws[WS_SUMW + c]) : 0.0f;
    }
    #pragma unroll
    for (int i = 0; i < 4; ++i) {
        int b = row0 + ty * 4 + i;
        float pf = ws[WS_NF + b] + 2.0f * EPSV * ws[WS_SUMF + b];
        if (cbase + 3 < NC) {
            float4 o;
            o.x = proto - sqrtf(fmaxf(pf + pw[0] + de2 - 2.0f * acc[i][0], 0.0f));
            o.y = proto - sqrtf(fmaxf(pf + pw[1] + de2 - 2.0f * acc[i][1], 0.0f));
            o.z = proto - sqrtf(fmaxf(pf + pw[2] + de2 - 2.0f * acc[i][2], 0.0f));
            o.w = proto - sqrtf(fmaxf(pf + pw[3] + de2 - 2.0f * acc[i][3], 0.0f));
            *(float4*)(out + b * NC + cbase) = o;
        } else {
            #pragma unroll
            for (int j = 0; j < 4; ++j) {
                int c = cbase + j;
                if (c < NC)
                    out[b * NC + c] = proto - sqrtf(fmaxf(pf + pw[j] + de2 - 2.0f * acc[i][j], 0.0f));
            }
        }
    }
}

extern "C" void kernel_launch(void* const* d_in, const int* in_sizes, int n_in,
                              void* d_out, int out_size, void* d_ws, size_t ws_size,
                              hipStream_t stream) {
    const float* F  = (const float*)d_in[0];   // (2048,128)
    const float* Wm = (const float*)d_in[1];   // (1000,128)
    float* out = (float*)d_out;                // (2048,1000)
    float* ws  = (float*)d_ws;

    // 3048 rows, one wave each, 4 waves per 256-thread block
    stats_kernel<<<762, 256, 0, stream>>>(F, Wm, ws);
    // C x C proto distances -> scalar
    proto_kernel<<<dim3(16, 16), 256, 0, stream>>>(Wm, ws);
    // B x C distances -> output
    dist_kernel<<<dim3(16, 32), 256, 0, stream>>>(F, Wm, ws, out);
}

// Round 2
// 85.183 us; speedup vs baseline: 1.0165x; 1.0165x over previous
//
#include <hip/hip_runtime.h>
#include <math.h>

#define DDIM 128
#define NB   2048
#define NC   1000
#define EPSV 1e-6f
#define TWOE (2.0f * EPSV)
#define TILE 64

// LDS layout (per tile, k-major, XOR-swizzled, no padding):
//   element (k, m) -> float index  k*64 + ((m>>2) ^ ((k>>2)&7))*4 + (m&3)
// Reads per k-step are ds_read_b128 (4 consecutive m), 16B-aligned, conflict-free.
// Staging writes hit 32 distinct banks per instruction (2-way aliasing = free).

__device__ __forceinline__ void stage_tile(const float* __restrict__ src,
                                           int row0, int row_clamp,
                                           float* __restrict__ lds, int t) {
    int kq  = t & 15;          // k-quad low 0..15
    int ty4 = (t >> 4) & 3;    // row low bits 0..3
    int tz  = t >> 6;          // 0..3
    #pragma unroll
    for (int it = 0; it < 4; ++it) {
        int r  = ty4 + 4 * tz + 16 * it;          // 0..63
        int gr = row0 + r; if (gr > row_clamp) gr = row_clamp;
        #pragma unroll
        for (int kc = 0; kc < 2; ++kc) {
            int kqq = kq + 16 * kc;               // 0..31
            float4 g = *(const float4*)(src + gr * DDIM + kqq * 4);
            int sblk = (r >> 2) ^ (kqq & 7);
            int base = kqq * 4 * TILE + sblk * 4 + (r & 3);
            lds[base           ] = g.x;
            lds[base + TILE    ] = g.y;
            lds[base + 2 * TILE] = g.z;
            lds[base + 3 * TILE] = g.w;
        }
    }
}

// Computes 64x64 tile of A·B^T (rows from ldsA, rows from ldsB), with fused
// per-row stats: pA[i] = sum a(a+2eps) over K, pB[j] = sum b(b-2eps) over K.
__device__ __forceinline__ void gemm_tile(const float* __restrict__ As,
                                          const float* __restrict__ Bs,
                                          int tyc, int txc,
                                          float acc[4][4], float pA[4], float pB[4]) {
    #pragma unroll 4
    for (int g = 0; g < 32; ++g) {                // k-group: k = g*4+q
        int s = g & 7;
        const float4* ap = (const float4*)(As + g * 256 + (tyc ^ s) * 4);
        const float4* bp = (const float4*)(Bs + g * 256 + (txc ^ s) * 4);
        #pragma unroll
        for (int q = 0; q < 4; ++q) {
            float4 a4 = ap[q * 16];
            float4 b4 = bp[q * 16];
            float av[4] = {a4.x, a4.y, a4.z, a4.w};
            float bv[4] = {b4.x, b4.y, b4.z, b4.w};
            #pragma unroll
            for (int i = 0; i < 4; ++i) pA[i] = fmaf(av[i], av[i] + TWOE, pA[i]);
            #pragma unroll
            for (int j = 0; j < 4; ++j) pB[j] = fmaf(bv[j], bv[j] - TWOE, pB[j]);
            #pragma unroll
            for (int i = 0; i < 4; ++i)
                #pragma unroll
                for (int j = 0; j < 4; ++j)
                    acc[i][j] = fmaf(av[i], bv[j], acc[i][j]);
        }
    }
}

// -------- proto: sum_{c1,c2} ||w_c1 - w_c2 + eps||  -> atomicAdd ws[0] --------
__global__ __launch_bounds__(256, 2) void proto_kernel(const float* __restrict__ Wm,
                                                       float* __restrict__ ws) {
    __shared__ __align__(16) float As[TILE * DDIM];
    __shared__ __align__(16) float Bs[TILE * DDIM];
    __shared__ float red[4];
    int t = threadIdx.x;
    int row0 = blockIdx.y * TILE, col0 = blockIdx.x * TILE;
    stage_tile(Wm, row0, NC - 1, As, t);
    stage_tile(Wm, col0, NC - 1, Bs, t);
    __syncthreads();
    int txc = t & 15, tyc = t >> 4;
    float acc[4][4] = {}, pA[4] = {}, pB[4] = {};
    gemm_tile(As, Bs, tyc, txc, acc, pA, pB);
    const float de2 = DDIM * EPSV * EPSV;
    float local = 0.0f;
    #pragma unroll
    for (int i = 0; i < 4; ++i) {
        int c1 = row0 + tyc * 4 + i;
        if (c1 < NC) {
            #pragma unroll
            for (int j = 0; j < 4; ++j) {
                int c2 = col0 + txc * 4 + j;
                if (c2 < NC) {
                    float d2 = pA[i] + pB[j] + de2 - 2.0f * acc[i][j];
                    local += sqrtf(fmaxf(d2, 0.0f));
                }
            }
        }
    }
    #pragma unroll
    for (int off = 32; off > 0; off >>= 1) local += __shfl_down(local, off);
    if ((t & 63) == 0) red[t >> 6] = local;
    __syncthreads();
    if (t == 0) atomicAdd(ws, red[0] + red[1] + red[2] + red[3]);
}

// -------- dist: out[b,c] = protoSum - ||f_b - w_c + eps|| ---------------------
__global__ __launch_bounds__(256, 2) void dist_kernel(const float* __restrict__ F,
                                                      const float* __restrict__ Wm,
                                                      const float* __restrict__ ws,
                                                      float* __restrict__ out) {
    __shared__ __align__(16) float As[TILE * DDIM];
    __shared__ __align__(16) float Bs[TILE * DDIM];
    int t = threadIdx.x;
    int row0 = blockIdx.y * TILE, col0 = blockIdx.x * TILE;
    stage_tile(F,  row0, NB - 1, As, t);
    stage_tile(Wm, col0, NC - 1, Bs, t);
    __syncthreads();
    int txc = t & 15, tyc = t >> 4;
    float acc[4][4] = {}, pA[4] = {}, pB[4] = {};
    gemm_tile(As, Bs, tyc, txc, acc, pA, pB);
    const float proto = ws[0];
    const float de2 = DDIM * EPSV * EPSV;
    int cbase = col0 + txc * 4;
    #pragma unroll
    for (int i = 0; i < 4; ++i) {
        int b = row0 + tyc * 4 + i;
        if (cbase + 3 < NC) {
            float4 o;
            o.x = proto - sqrtf(fmaxf(pA[i] + pB[0] + de2 - 2.0f * acc[i][0], 0.0f));
            o.y = proto - sqrtf(fmaxf(pA[i] + pB[1] + de2 - 2.0f * acc[i][1], 0.0f));
            o.z = proto - sqrtf(fmaxf(pA[i] + pB[2] + de2 - 2.0f * acc[i][2], 0.0f));
            o.w = proto - sqrtf(fmaxf(pA[i] + pB[3] + de2 - 2.0f * acc[i][3], 0.0f));
            *(float4*)(out + b * NC + cbase) = o;
        } else {
            #pragma unroll
            for (int j = 0; j < 4; ++j) {
                int c = cbase + j;
                if (c < NC)
                    out[b * NC + c] = proto - sqrtf(fmaxf(pA[i] + pB[j] + de2 - 2.0f * acc[i][j], 0.0f));
            }
        }
    }
}

extern "C" void kernel_launch(void* const* d_in, const int* in_sizes, int n_in,
                              void* d_out, int out_size, void* d_ws, size_t ws_size,
                              hipStream_t stream) {
    const float* F  = (const float*)d_in[0];   // (2048,128)
    const float* Wm = (const float*)d_in[1];   // (1000,128)
    float* out = (float*)d_out;                // (2048,1000)
    float* ws  = (float*)d_ws;

    hipMemsetAsync(ws, 0, sizeof(float), stream);       // zero atomic target
    proto_kernel<<<dim3(16, 16), 256, 0, stream>>>(Wm, ws);
    dist_kernel <<<dim3(16, 32), 256, 0, stream>>>(F, Wm, ws, out);
}

// Round 3
// 71.404 us; speedup vs baseline: 1.2127x; 1.1930x over previous
//
#include <hip/hip_runtime.h>
#include <math.h>

#define NB   2048
#define NC   1000
#define DDIM 128
#define LDT  136   // LDS row stride in bf16 (+8 pad: fragment reads 2-way = free)

// ws float-index layout (all regions fully rewritten every launch)
#define WS_PROTO 0
#define WS_NF    16                          // [16 .. 16+2048)
#define WS_NW    (16 + NB)                   // [2064 .. 3064)
#define WS_FB_F  3072                        // bf16 F: 2048*128 ushorts = 131072 floats
#define WS_WB_F  (WS_FB_F + (NB * DDIM) / 2) // 134144; bf16 W: 1000*128 ushorts

typedef __attribute__((ext_vector_type(8))) short  short8;
typedef __attribute__((ext_vector_type(4))) float  floatx4;

__device__ __forceinline__ unsigned short f2bf(float x) {
    union { float f; unsigned int u; } v; v.f = x;
    unsigned int r = (v.u + 0x7FFFu + ((v.u >> 16) & 1u)) >> 16;  // RNE
    return (unsigned short)r;
}
__device__ __forceinline__ float bf2f(unsigned short b) {
    union { float f; unsigned int u; } v; v.u = ((unsigned int)b) << 16;
    return v.f;
}

// ---- convert fp32 -> bf16 rows + fp32 norms of the ROUNDED values ------------
__global__ __launch_bounds__(256) void convert_kernel(const float* __restrict__ F,
                                                      const float* __restrict__ W,
                                                      float* __restrict__ ws) {
    if (blockIdx.x == 0 && threadIdx.x == 0) ws[WS_PROTO] = 0.0f;
    int gw   = (blockIdx.x * 256 + threadIdx.x) >> 6;
    int lane = threadIdx.x & 63;
    if (gw >= NB + NC) return;
    unsigned short* FB = (unsigned short*)(ws + WS_FB_F);
    unsigned short* WB = (unsigned short*)(ws + WS_WB_F);
    const float* row; unsigned short* dst; int nidx;
    if (gw < NB) { row = F + gw * DDIM;            dst = FB + gw * DDIM; nidx = WS_NF + gw; }
    else { int c = gw - NB; row = W + c * DDIM;    dst = WB + c * DDIM;  nidx = WS_NW + c; }
    float2 v = *(const float2*)(row + lane * 2);
    unsigned short bx = f2bf(v.x), by = f2bf(v.y);
    float fx = bf2f(bx), fy = bf2f(by);
    float qn = fx * fx + fy * fy;
    ushort2 st; st.x = bx; st.y = by;
    *(ushort2*)(dst + lane * 2) = st;
    #pragma unroll
    for (int off = 32; off > 0; off >>= 1) qn += __shfl_down(qn, off);
    if (lane == 0) ws[nidx] = qn;
}

// ---- stage a 64-row x 128-k bf16 tile into padded LDS ------------------------
__device__ __forceinline__ void stage64(const unsigned short* __restrict__ src,
                                        int row0, int rclamp,
                                        unsigned short* __restrict__ lds, int t) {
    #pragma unroll
    for (int it = 0; it < 4; ++it) {
        int c = t + 256 * it;
        int r = c >> 4, kc = c & 15;
        int gr = row0 + r; if (gr > rclamp) gr = rclamp;
        short8 v = *(const short8*)(src + gr * DDIM + kc * 8);
        *(short8*)(lds + r * LDT + kc * 8) = v;
    }
}

// ---- 64x64 block tile: 4 waves, each a 2x2 of 16x16x32 MFMA tiles ------------
__device__ __forceinline__ void gemm64(const unsigned short* __restrict__ As,
                                       const unsigned short* __restrict__ Bs,
                                       int lane, int w, floatx4 acc[2][2]) {
    int wm = (w >> 1) * 32, wn = (w & 1) * 32;
    int lm = lane & 15, q = lane >> 4;
    #pragma unroll
    for (int ks = 0; ks < 4; ++ks) {
        int ko = ks * 32 + q * 8;
        short8 a0 = *(const short8*)(As + (wm + lm) * LDT + ko);
        short8 a1 = *(const short8*)(As + (wm + 16 + lm) * LDT + ko);
        short8 b0 = *(const short8*)(Bs + (wn + lm) * LDT + ko);
        short8 b1 = *(const short8*)(Bs + (wn + 16 + lm) * LDT + ko);
        acc[0][0] = __builtin_amdgcn_mfma_f32_16x16x32_bf16(a0, b0, acc[0][0], 0, 0, 0);
        acc[0][1] = __builtin_amdgcn_mfma_f32_16x16x32_bf16(a0, b1, acc[0][1], 0, 0, 0);
        acc[1][0] = __builtin_amdgcn_mfma_f32_16x16x32_bf16(a1, b0, acc[1][0], 0, 0, 0);
        acc[1][1] = __builtin_amdgcn_mfma_f32_16x16x32_bf16(a1, b1, acc[1][1], 0, 0, 0);
    }
}

// ---- proto: sum_{c1,c2} ||w_c1 - w_c2|| -> atomicAdd ws[WS_PROTO] ------------
__global__ __launch_bounds__(256) void proto_kernel(float* __restrict__ ws) {
    __shared__ __align__(16) unsigned short As[64 * LDT];
    __shared__ __align__(16) unsigned short Bs[64 * LDT];
    __shared__ float red[4];
    const unsigned short* WB = (const unsigned short*)(ws + WS_WB_F);
    int t = threadIdx.x;
    int row0 = blockIdx.y * 64, col0 = blockIdx.x * 64;
    stage64(WB, row0, NC - 1, As, t);
    stage64(WB, col0, NC - 1, Bs, t);
    __syncthreads();
    int lane = t & 63, w = t >> 6;
    floatx4 acc[2][2] = {{{0,0,0,0},{0,0,0,0}},{{0,0,0,0},{0,0,0,0}}};
    gemm64(As, Bs, lane, w, acc);
    int wm = (w >> 1) * 32, wn = (w & 1) * 32;
    int lm = lane & 15, q = lane >> 4;
    float local = 0.0f;
    #pragma unroll
    for (int ti = 0; ti < 2; ++ti) {
        #pragma unroll
        for (int tj = 0; tj < 2; ++tj) {
            int c2 = col0 + wn + tj * 16 + lm;
            if (c2 < NC) {
                float n2 = ws[WS_NW + c2];
                #pragma unroll
                for (int r = 0; r < 4; ++r) {
                    int c1 = row0 + wm + ti * 16 + q * 4 + r;
                    if (c1 < NC) {
                        float d2 = ws[WS_NW + c1] + n2 - 2.0f * acc[ti][tj][r];
                        local += sqrtf(fmaxf(d2, 0.0f));
                    }
                }
            }
        }
    }
    #pragma unroll
    for (int off = 32; off > 0; off >>= 1) local += __shfl_down(local, off);
    if ((t & 63) == 0) red[t >> 6] = local;
    __syncthreads();
    if (t == 0) atomicAdd(ws + WS_PROTO, red[0] + red[1] + red[2] + red[3]);
}

// ---- dist: out[b,c] = protoSum - ||f_b - w_c|| -------------------------------
__global__ __launch_bounds__(256) void dist_kernel(const float* __restrict__ ws,
                                                   float* __restrict__ out) {
    __shared__ __align__(16) unsigned short As[64 * LDT];
    __shared__ __align__(16) unsigned short Bs[64 * LDT];
    const unsigned short* FB = (const unsigned short*)(ws + WS_FB_F);
    const unsigned short* WB = (const unsigned short*)(ws + WS_WB_F);
    int t = threadIdx.x;
    int row0 = blockIdx.y * 64, col0 = blockIdx.x * 64;
    stage64(FB, row0, NB - 1, As, t);
    stage64(WB, col0, NC - 1, Bs, t);
    __syncthreads();
    int lane = t & 63, w = t >> 6;
    floatx4 acc[2][2] = {{{0,0,0,0},{0,0,0,0}},{{0,0,0,0},{0,0,0,0}}};
    gemm64(As, Bs, lane, w, acc);
    float proto = ws[WS_PROTO];
    int wm = (w >> 1) * 32, wn = (w & 1) * 32;
    int lm = lane & 15, q = lane >> 4;
    #pragma unroll
    for (int ti = 0; ti < 2; ++ti) {
        #pragma unroll
        for (int tj = 0; tj < 2; ++tj) {
            int cg = col0 + wn + tj * 16 + lm;
            if (cg < NC) {
                float n2 = ws[WS_NW + cg];
                #pragma unroll
                for (int r = 0; r < 4; ++r) {
                    int mg = row0 + wm + ti * 16 + q * 4 + r;
                    float d2 = ws[WS_NF + mg] + n2 - 2.0f * acc[ti][tj][r];
                    out[mg * NC + cg] = proto - sqrtf(fmaxf(d2, 0.0f));
                }
            }
        }
    }
}

extern "C" void kernel_launch(void* const* d_in, const int* in_sizes, int n_in,
                              void* d_out, int out_size, void* d_ws, size_t ws_size,
                              hipStream_t stream) {
    const float* F  = (const float*)d_in[0];   // (2048,128)
    const float* Wm = (const float*)d_in[1];   // (1000,128)
    float* out = (float*)d_out;                // (2048,1000)
    float* ws  = (float*)d_ws;

    convert_kernel<<<762, 256, 0, stream>>>(F, Wm, ws);          // 3048 rows, 1 wave/row
    proto_kernel  <<<dim3(16, 16), 256, 0, stream>>>(ws);        // C x C -> scalar
    dist_kernel   <<<dim3(16, 32), 256, 0, stream>>>(ws, out);   // B x C -> out
}